// Round 1
// baseline (128.458 us; speedup 1.0000x reference)
//
#include <hip/hip_runtime.h>
#include <hip/hip_bf16.h>

// Problem constants (fixed by reference): N=4096, D=256, T=0.5, EPS=1e-8
#define PN   4096
#define PN2  8192
#define PD   256
#define TILE 128
#define BK   64

typedef __attribute__((ext_vector_type(8))) short bf16x8;   // 8 bf16 = 4 VGPRs
typedef __attribute__((ext_vector_type(4))) float f32x4;

typedef const __attribute__((address_space(1))) void* gas_ptr;
typedef __attribute__((address_space(3))) void* las_ptr;

// ---------------------------------------------------------------------------
// Kernel 1: row-normalize z = [z_i; z_j] (fp32), write bf16 zn, zero rowsum
// ---------------------------------------------------------------------------
__global__ __launch_bounds__(256) void normalize_kernel(
    const float* __restrict__ zi, const float* __restrict__ zj,
    __hip_bfloat16* __restrict__ zn, float* __restrict__ rowsum) {
  int r = blockIdx.x;          // 0..8191
  int tid = threadIdx.x;       // 0..255 == D
  const float* src = (r < PN) ? (zi + (size_t)r * PD) : (zj + (size_t)(r - PN) * PD);
  float x = src[tid];
  float s = x * x;
  #pragma unroll
  for (int off = 32; off >= 1; off >>= 1) s += __shfl_xor(s, off, 64);
  __shared__ float p[4];
  if ((tid & 63) == 0) p[tid >> 6] = s;
  __syncthreads();
  float tot = p[0] + p[1] + p[2] + p[3];
  float nrm = fmaxf(sqrtf(tot), 1e-8f);
  zn[(size_t)r * PD + tid] = __float2bfloat16(x / nrm);
  if (tid == 0) rowsum[r] = 0.0f;   // ws is re-poisoned 0xAA before every launch
}

// ---------------------------------------------------------------------------
// Kernel 2: tiled sim = zn @ zn^T with fused exp-rowsum + positives capture.
// 128x128 tile per block, 4 waves, each wave a 64x64 subtile (4x4 MFMA tiles).
// LDS staging via global_load_lds width=16, XOR chunk swizzle for bank spread.
// ---------------------------------------------------------------------------
__global__ __launch_bounds__(256) void simsum_kernel(
    const __hip_bfloat16* __restrict__ zn,
    float* __restrict__ rowsum, float* __restrict__ pos) {
  __shared__ char lds[2 * TILE * BK * 2];   // 32 KiB: As then Bs
  char* As = lds;
  char* Bs = lds + TILE * BK * 2;

  const int tid  = threadIdx.x;
  const int wave = tid >> 6;
  const int lane = tid & 63;
  const int quad = lane >> 4;
  const int c16  = lane & 15;
  const int rowBase = blockIdx.x * TILE;
  const int colBase = blockIdx.y * TILE;
  const int waveRow = (wave >> 1) * 64;
  const int waveCol = (wave & 1) * 64;

  f32x4 acc[4][4];
  #pragma unroll
  for (int i = 0; i < 4; ++i)
    #pragma unroll
    for (int j = 0; j < 4; ++j)
      acc[i][j] = (f32x4){0.f, 0.f, 0.f, 0.f};

  const int subrow = lane >> 3;  // 0..7 (row within an 8-row issue)
  const int slot   = lane & 7;   // 0..7 (16B chunk slot within a 128B LDS row)

  for (int kt = 0; kt < PD / BK; ++kt) {
    if (kt) __syncthreads();     // protect LDS before overwrite
    #pragma unroll
    for (int p = 0; p < 4; ++p) {
      int issue = wave * 4 + p;            // 0..15, wave-uniform
      int r = issue * 8 + subrow;          // tile row 0..127
      int c = slot ^ (r & 7);              // swizzled: which k-chunk this lane fetches
      const __hip_bfloat16* ga = zn + (size_t)(rowBase + r) * PD + kt * BK + c * 8;
      __builtin_amdgcn_global_load_lds((gas_ptr)ga, (las_ptr)(As + issue * 1024), 16, 0, 0);
      const __hip_bfloat16* gb = zn + (size_t)(colBase + r) * PD + kt * BK + c * 8;
      __builtin_amdgcn_global_load_lds((gas_ptr)gb, (las_ptr)(Bs + issue * 1024), 16, 0, 0);
    }
    __syncthreads();             // emits s_waitcnt vmcnt(0) before s_barrier

    #pragma unroll
    for (int ki = 0; ki < 2; ++ki) {       // two k=32 MFMA steps per BK=64
      bf16x8 a[4], b[4];
      #pragma unroll
      for (int mi = 0; mi < 4; ++mi) {
        int r = waveRow + mi * 16 + c16;   // A row: m = lane&15
        int ch = quad + ki * 4;            // k-chunk: k = ki*32 + quad*8 + j
        a[mi] = *(const bf16x8*)(As + r * 128 + ((ch ^ (r & 7)) * 16));
      }
      #pragma unroll
      for (int ni = 0; ni < 4; ++ni) {
        int r = waveCol + ni * 16 + c16;   // B "row" of zn = sim column n = lane&15
        int ch = quad + ki * 4;
        b[ni] = *(const bf16x8*)(Bs + r * 128 + ((ch ^ (r & 7)) * 16));
      }
      #pragma unroll
      for (int mi = 0; mi < 4; ++mi)
        #pragma unroll
        for (int ni = 0; ni < 4; ++ni)
          acc[mi][ni] = __builtin_amdgcn_mfma_f32_16x16x32_bf16(a[mi], b[ni], acc[mi][ni], 0, 0, 0);
    }
  }

  // Epilogue: C/D layout col=lane&15, row=quad*4+reg  [measured m89/m91]
  #pragma unroll
  for (int mi = 0; mi < 4; ++mi) {
    int rbase = rowBase + waveRow + mi * 16 + quad * 4;
    float rs[4] = {0.f, 0.f, 0.f, 0.f};
    #pragma unroll
    for (int ni = 0; ni < 4; ++ni) {
      int gcol = colBase + waveCol + ni * 16 + c16;
      #pragma unroll
      for (int t = 0; t < 4; ++t) {
        int grow = rbase + t;
        float sim = acc[mi][ni][t];
        if (gcol == (grow ^ PN)) pos[grow] = sim;       // (row+N) mod 2N == row^4096
        rs[t] += (gcol == grow) ? 0.0f : __expf(2.0f * sim);  // sim/T, diag masked
      }
    }
    #pragma unroll
    for (int t = 0; t < 4; ++t) {
      #pragma unroll
      for (int off = 1; off <= 8; off <<= 1) rs[t] += __shfl_xor(rs[t], off, 64);
    }
    if (c16 == 0) {
      #pragma unroll
      for (int t = 0; t < 4; ++t) atomicAdd(&rowsum[rbase + t], rs[t]);
    }
  }
}

// ---------------------------------------------------------------------------
// Kernel 3: loss_i = log(denom_i) - 2*pos_i ; out = sum(w*loss)/sum(w)
// ---------------------------------------------------------------------------
__global__ __launch_bounds__(256) void finalize_kernel(
    const float* __restrict__ rowsum, const float* __restrict__ pos,
    const float* __restrict__ w, float* __restrict__ out) {
  int tid = threadIdx.x;
  float wl = 0.f, ws = 0.f;
  for (int i = tid; i < PN2; i += 256) {
    float li = logf(rowsum[i]) - 2.0f * pos[i];
    float wi = w[i & (PN - 1)];
    wl += wi * li;
    ws += wi;
  }
  #pragma unroll
  for (int off = 32; off >= 1; off >>= 1) {
    wl += __shfl_xor(wl, off, 64);
    ws += __shfl_xor(ws, off, 64);
  }
  __shared__ float pl[4], pw[4];
  if ((tid & 63) == 0) { pl[tid >> 6] = wl; pw[tid >> 6] = ws; }
  __syncthreads();
  if (tid == 0)
    out[0] = (pl[0] + pl[1] + pl[2] + pl[3]) / (pw[0] + pw[1] + pw[2] + pw[3]);
}

// ---------------------------------------------------------------------------
extern "C" void kernel_launch(void* const* d_in, const int* in_sizes, int n_in,
                              void* d_out, int out_size, void* d_ws, size_t ws_size,
                              hipStream_t stream) {
  const float* zi = (const float*)d_in[0];
  const float* zj = (const float*)d_in[1];
  const float* w  = (const float*)d_in[2];
  float* out = (float*)d_out;

  // Workspace: zn bf16 [8192*256] = 4 MiB, then rowsum f32[8192], pos f32[8192]
  __hip_bfloat16* zn = (__hip_bfloat16*)d_ws;
  float* rowsum = (float*)((char*)d_ws + (size_t)PN2 * PD * 2);
  float* pos = rowsum + PN2;

  normalize_kernel<<<PN2, 256, 0, stream>>>(zi, zj, zn, rowsum);
  dim3 grid(PN2 / TILE, PN2 / TILE);
  simsum_kernel<<<grid, 256, 0, stream>>>(zn, rowsum, pos);
  finalize_kernel<<<1, 256, 0, stream>>>(rowsum, pos, w, out);
}

// Round 2
// 108.639 us; speedup vs baseline: 1.1824x; 1.1824x over previous
//
#include <hip/hip_runtime.h>
#include <hip/hip_bf16.h>

// Problem constants (fixed by reference): N=4096, D=256, T=0.5, EPS=1e-8
#define PN   4096
#define PN2  8192
#define PD   256
#define TILE 128
#define BK   64
#define NBLK (PN2 / TILE)          // 64 tile-blocks per dim
#define NTRI (NBLK * (NBLK + 1) / 2)  // 2080 upper-tri blocks

typedef __attribute__((ext_vector_type(8))) short bf16x8;   // 8 bf16 = 4 VGPRs
typedef __attribute__((ext_vector_type(4))) float f32x4;

typedef const __attribute__((address_space(1))) void* gas_ptr;
typedef __attribute__((address_space(3))) void* las_ptr;

// ---------------------------------------------------------------------------
// Kernel 1: row-normalize z = [z_i; z_j] (fp32), write bf16 zn, zero rowsum
// ---------------------------------------------------------------------------
__global__ __launch_bounds__(256) void normalize_kernel(
    const float* __restrict__ zi, const float* __restrict__ zj,
    __hip_bfloat16* __restrict__ zn, float* __restrict__ rowsum) {
  int r = blockIdx.x;          // 0..8191
  int tid = threadIdx.x;       // 0..255 == D
  const float* src = (r < PN) ? (zi + (size_t)r * PD) : (zj + (size_t)(r - PN) * PD);
  float x = src[tid];
  float s = x * x;
  #pragma unroll
  for (int off = 32; off >= 1; off >>= 1) s += __shfl_xor(s, off, 64);
  __shared__ float p[4];
  if ((tid & 63) == 0) p[tid >> 6] = s;
  __syncthreads();
  float tot = p[0] + p[1] + p[2] + p[3];
  float nrm = fmaxf(sqrtf(tot), 1e-8f);
  zn[(size_t)r * PD + tid] = __float2bfloat16(x / nrm);
  if (tid == 0) rowsum[r] = 0.0f;   // ws is re-poisoned 0xAA before every launch
}

// ---------------------------------------------------------------------------
// Kernel 2: sim = zn @ zn^T, UPPER-TRIANGULAR blocks only (symmetry).
// Off-diag block (bi<bj): exp-tile reduced along BOTH axes -> rowsum[row] and
// rowsum[col]. Diag block (bi==bj): full tile, row-reduce only, B-stage skipped.
// Positives live in bj==bi+32 blocks; write pos[grow] and pos[grow+N] (symmetric).
// ---------------------------------------------------------------------------
__global__ __launch_bounds__(256) void simsum_kernel(
    const __hip_bfloat16* __restrict__ zn,
    float* __restrict__ rowsum, float* __restrict__ pos) {
  __shared__ char lds[2 * TILE * BK * 2];   // 32 KiB: As then Bs
  char* As = lds;
  char* Bs = lds + TILE * BK * 2;

  // Decode upper-tri (bi<=bj) from linear index: bj columns, T(bj)=bj(bj+1)/2
  const int idx = blockIdx.x;
  int bj = (int)((sqrtf(8.0f * (float)idx + 1.0f) - 1.0f) * 0.5f);
  while ((bj + 1) * (bj + 2) / 2 <= idx) ++bj;
  while (bj * (bj + 1) / 2 > idx) --bj;
  const int bi = idx - bj * (bj + 1) / 2;
  const bool diagBlk = (bi == bj);
  const bool posBlk  = (bj == bi + PN / TILE);   // cols == rows + 4096

  const int tid  = threadIdx.x;
  const int wave = tid >> 6;
  const int lane = tid & 63;
  const int quad = lane >> 4;
  const int c16  = lane & 15;
  const int rowBase = bi * TILE;
  const int colBase = bj * TILE;
  const int waveRow = (wave >> 1) * 64;
  const int waveCol = (wave & 1) * 64;

  f32x4 acc[4][4];
  #pragma unroll
  for (int i = 0; i < 4; ++i)
    #pragma unroll
    for (int j = 0; j < 4; ++j)
      acc[i][j] = (f32x4){0.f, 0.f, 0.f, 0.f};

  const int subrow = lane >> 3;  // 0..7 (row within an 8-row issue)
  const int slot   = lane & 7;   // 0..7 (16B chunk slot within a 128B LDS row)
  const char* BsEff = diagBlk ? As : Bs;

  for (int kt = 0; kt < PD / BK; ++kt) {
    if (kt) __syncthreads();     // protect LDS before overwrite
    #pragma unroll
    for (int p = 0; p < 4; ++p) {
      int issue = wave * 4 + p;            // 0..15, wave-uniform
      int r = issue * 8 + subrow;          // tile row 0..127
      int c = slot ^ (r & 7);              // swizzled k-chunk for this lane
      const __hip_bfloat16* ga = zn + (size_t)(rowBase + r) * PD + kt * BK + c * 8;
      __builtin_amdgcn_global_load_lds((gas_ptr)ga, (las_ptr)(As + issue * 1024), 16, 0, 0);
      if (!diagBlk) {
        const __hip_bfloat16* gb = zn + (size_t)(colBase + r) * PD + kt * BK + c * 8;
        __builtin_amdgcn_global_load_lds((gas_ptr)gb, (las_ptr)(Bs + issue * 1024), 16, 0, 0);
      }
    }
    __syncthreads();             // s_waitcnt vmcnt(0) before s_barrier

    #pragma unroll
    for (int ki = 0; ki < 2; ++ki) {       // two k=32 MFMA steps per BK=64
      bf16x8 a[4], b[4];
      #pragma unroll
      for (int mi = 0; mi < 4; ++mi) {
        int r = waveRow + mi * 16 + c16;   // A row: m = lane&15
        int ch = quad + ki * 4;            // k-chunk: k = ki*32 + quad*8 + j
        a[mi] = *(const bf16x8*)(As + r * 128 + ((ch ^ (r & 7)) * 16));
      }
      #pragma unroll
      for (int ni = 0; ni < 4; ++ni) {
        int r = waveCol + ni * 16 + c16;   // B "row" of zn = sim column n
        int ch = quad + ki * 4;
        b[ni] = *(const bf16x8*)(BsEff + r * 128 + ((ch ^ (r & 7)) * 16));
      }
      #pragma unroll
      for (int mi = 0; mi < 4; ++mi)
        #pragma unroll
        for (int ni = 0; ni < 4; ++ni)
          acc[mi][ni] = __builtin_amdgcn_mfma_f32_16x16x32_bf16(a[mi], b[ni], acc[mi][ni], 0, 0, 0);
    }
  }

  // Epilogue. C/D layout: col=lane&15, row=quad*4+reg  [measured m89/m91]
  float colsum[4] = {0.f, 0.f, 0.f, 0.f};   // per-ni column partials (off-diag)
  #pragma unroll
  for (int mi = 0; mi < 4; ++mi) {
    int rbase = rowBase + waveRow + mi * 16 + quad * 4;
    float rs[4] = {0.f, 0.f, 0.f, 0.f};
    #pragma unroll
    for (int ni = 0; ni < 4; ++ni) {
      int gcol = colBase + waveCol + ni * 16 + c16;
      #pragma unroll
      for (int t = 0; t < 4; ++t) {
        int grow = rbase + t;
        float sim = acc[mi][ni][t];
        float e = __expf(2.0f * sim);               // exp(sim / T), T=0.5
        if (diagBlk && gcol == grow) e = 0.0f;      // mask diagonal
        rs[t] += e;
        colsum[ni] += e;
        if (posBlk && gcol == grow + PN) {          // positive pair (and mirror)
          pos[grow] = sim;
          pos[grow + PN] = sim;
        }
      }
    }
    #pragma unroll
    for (int t = 0; t < 4; ++t) {
      #pragma unroll
      for (int off = 1; off <= 8; off <<= 1) rs[t] += __shfl_xor(rs[t], off, 64);
    }
    if (c16 == 0) {
      #pragma unroll
      for (int t = 0; t < 4; ++t) atomicAdd(&rowsum[rbase + t], rs[t]);
    }
  }
  if (!diagBlk) {   // column contributions = mirrored rows (symmetry)
    #pragma unroll
    for (int ni = 0; ni < 4; ++ni) {
      float cs = colsum[ni];
      cs += __shfl_xor(cs, 16, 64);
      cs += __shfl_xor(cs, 32, 64);
      if (quad == 0) atomicAdd(&rowsum[colBase + waveCol + ni * 16 + c16], cs);
    }
  }
}

// ---------------------------------------------------------------------------
// Kernel 3: loss_i = log(denom_i) - 2*pos_i ; out = sum(w*loss)/sum(w)
// ---------------------------------------------------------------------------
__global__ __launch_bounds__(1024) void finalize_kernel(
    const float* __restrict__ rowsum, const float* __restrict__ pos,
    const float* __restrict__ w, float* __restrict__ out) {
  int tid = threadIdx.x;
  float wl = 0.f, ws = 0.f;
  for (int i = tid; i < PN2; i += 1024) {
    float li = logf(rowsum[i]) - 2.0f * pos[i];
    float wi = w[i & (PN - 1)];
    wl += wi * li;
    ws += wi;
  }
  #pragma unroll
  for (int off = 32; off >= 1; off >>= 1) {
    wl += __shfl_xor(wl, off, 64);
    ws += __shfl_xor(ws, off, 64);
  }
  __shared__ float pl[16], pw[16];
  if ((tid & 63) == 0) { pl[tid >> 6] = wl; pw[tid >> 6] = ws; }
  __syncthreads();
  if (tid == 0) {
    float sl = 0.f, sw = 0.f;
    #pragma unroll
    for (int k = 0; k < 16; ++k) { sl += pl[k]; sw += pw[k]; }
    out[0] = sl / sw;
  }
}

// ---------------------------------------------------------------------------
extern "C" void kernel_launch(void* const* d_in, const int* in_sizes, int n_in,
                              void* d_out, int out_size, void* d_ws, size_t ws_size,
                              hipStream_t stream) {
  const float* zi = (const float*)d_in[0];
  const float* zj = (const float*)d_in[1];
  const float* w  = (const float*)d_in[2];
  float* out = (float*)d_out;

  // Workspace: zn bf16 [8192*256] = 4 MiB, then rowsum f32[8192], pos f32[8192]
  __hip_bfloat16* zn = (__hip_bfloat16*)d_ws;
  float* rowsum = (float*)((char*)d_ws + (size_t)PN2 * PD * 2);
  float* pos = rowsum + PN2;

  normalize_kernel<<<PN2, 256, 0, stream>>>(zi, zj, zn, rowsum);
  simsum_kernel<<<NTRI, 256, 0, stream>>>(zn, rowsum, pos);
  finalize_kernel<<<1, 1024, 0, stream>>>(rowsum, pos, w, out);
}